// Round 6
// baseline (302.889 us; speedup 1.0000x reference)
//
#include <hip/hip_runtime.h>

typedef unsigned short ushort_t;
typedef __attribute__((ext_vector_type(8))) short short8;
typedef __attribute__((ext_vector_type(4))) float floatx4;

#define DD 256
#define LL 3
#define GG 4
#define KK 128
#define UU 64
#define OUTN 10
#define HSTRIDE 264   // 256 + 8 bf16 pad; 528B row stride
#define MROWS 64      // rows per block -> 33792B LDS -> 4 blocks/CU

__device__ __forceinline__ ushort_t f2bf(float f) {
  unsigned u = __builtin_bit_cast(unsigned, f);
  u = (u + 0x7FFFu + ((u >> 16) & 1u)) >> 16;
  return (ushort_t)u;
}

// pack two f32 -> two bf16: 2 adds + 1 v_perm_b32
__device__ __forceinline__ unsigned pack_bf2(float lo, float hi) {
  unsigned a = __builtin_bit_cast(unsigned, hi) + 0x8000u;
  unsigned b = __builtin_bit_cast(unsigned, lo) + 0x8000u;
  return __builtin_amdgcn_perm(a, b, 0x07060302u);
}

// tanh(x) = 1 - 2/(e^{2x}+1); branch-free, exact at overflow
__device__ __forceinline__ float fast_tanh(float x) {
  float e = __builtin_amdgcn_exp2f(x * 2.885390081777927f);
  return __builtin_fmaf(-2.0f, __builtin_amdgcn_rcpf(e + 1.0f), 1.0f);
}

// AT[l][n][k] = sum_{j: idx[l,g,j]==k} W[l,g,j,u]  (n = g*64+u), bf16.
// WoT[n][k] = W_out[k][n] (n<10 else 0), 16x256 bf16.
__global__ __launch_bounds__(256) void prep_kernel(
    const int* __restrict__ idx, const float* __restrict__ W,
    const float* __restrict__ Wout, ushort_t* __restrict__ AT,
    ushort_t* __restrict__ WoT) {
  int b = blockIdx.x;
  int t = threadIdx.x;
  if (b < LL * DD) {
    int l = b >> 8, n = b & 255, g = n >> 6, u = n & 63;
    __shared__ int sidx[KK];
    __shared__ float sw[KK];
    if (t < KK) {
      sidx[t] = idx[(l * GG + g) * KK + t];
      sw[t]   = W[((size_t)((l * GG + g) * KK + t)) * UU + u];
    }
    __syncthreads();
    float s = 0.f;
#pragma unroll 8
    for (int j = 0; j < KK; j++) s += (sidx[j] == t) ? sw[j] : 0.f;
    AT[(b << 8) | t] = f2bf(s);
  } else {
    int e2 = (b - LL * DD) * 256 + t;
    int n = e2 >> 8, k = e2 & 255;
    WoT[e2] = (n < OUTN) ? f2bf(Wout[k * OUTN + n]) : (ushort_t)0;
  }
}

__global__ __launch_bounds__(256, 4) void fused_kernel(
    const float* __restrict__ x, const float* __restrict__ bias,
    const float* __restrict__ bout, const ushort_t* __restrict__ AT,
    const ushort_t* __restrict__ WoT, float* __restrict__ out) {
  __shared__ ushort_t hbuf[MROWS * HSTRIDE];  // 33792 B -> 4 blocks/CU

  const int tid  = threadIdx.x;
  const int wave = tid >> 6;     // wave == group g (64 cols each)
  const int lane = tid & 63;
  const int quad = lane >> 4;
  const int l16  = lane & 15;
  const long row0 = (long)blockIdx.x * MROWS;

  // ---- stage x tile (64 x 256 fp32) -> bf16 LDS ----
  const float4* xv = (const float4*)(x + row0 * DD);
#pragma unroll
  for (int i = 0; i < 16; i++) {
    int f  = tid + i * 256;      // 0..4095 float4s, 64 per row
    int r  = f >> 6;
    int c4 = f & 63;
    float4 v = xv[r * 64 + c4];
    uint2 w;
    w.x = pack_bf2(v.x, v.y);
    w.y = pack_bf2(v.z, v.w);
    *(uint2*)&hbuf[r * HSTRIDE + c4 * 4] = w;
  }
  __syncthreads();

  // ---- 3 levels. Operand-swap: Aop = AT rows (u), Bop = h rows (m).
  // D: col=l16 -> m_local, row=quad*4+r -> u_local. Bias folded into acc init.
#pragma unroll 1
  for (int l = 0; l < 3; l++) {
    const ushort_t* Ab = AT + l * (DD * DD) + (wave * UU + l16) * DD + quad * 8;
    const ushort_t* hsrc = hbuf + l16 * HSTRIDE + quad * 8;

    floatx4 acc[4][4];
#pragma unroll
    for (int nt = 0; nt < 4; nt++) {
      float4 bv = *(const float4*)&bias[(l * GG + wave) * UU + nt * 16 + quad * 4];
      floatx4 ini = {bv.x, bv.y, bv.z, bv.w};
#pragma unroll
      for (int mt = 0; mt < 4; mt++) acc[mt][nt] = ini;
    }

    short8 wf[4], wfn[4];
#pragma unroll
    for (int nt = 0; nt < 4; nt++) wf[nt] = *(const short8*)&Ab[nt * 16 * DD];

#pragma unroll
    for (int ks = 0; ks < 8; ks++) {
      if (ks < 7) {
#pragma unroll
        for (int nt = 0; nt < 4; nt++)
          wfn[nt] = *(const short8*)&Ab[nt * 16 * DD + (ks + 1) * 32];
      }
      // staggered LDS reads: 2 bf frags live at once
      short8 bfc = *(const short8*)&hsrc[0 * 16 * HSTRIDE + ks * 32];
#pragma unroll
      for (int mt = 0; mt < 4; mt++) {
        short8 bfn;
        if (mt < 3) bfn = *(const short8*)&hsrc[(mt + 1) * 16 * HSTRIDE + ks * 32];
#pragma unroll
        for (int nt = 0; nt < 4; nt++)
          acc[mt][nt] = __builtin_amdgcn_mfma_f32_16x16x32_bf16(wf[nt], bfc, acc[mt][nt], 0, 0, 0);
        bfc = bfn;
      }
#pragma unroll
      for (int nt = 0; nt < 4; nt++) wf[nt] = wfn[nt];
    }
    __syncthreads();  // all hbuf reads done before overwrite

    // epilogue: lane holds 4 consecutive u for row m = mt*16+l16 -> 8B writes
#pragma unroll
    for (int nt = 0; nt < 4; nt++) {
#pragma unroll
      for (int mt = 0; mt < 4; mt++) {
        uint2 w;
        w.x = pack_bf2(fast_tanh(acc[mt][nt][0]), fast_tanh(acc[mt][nt][1]));
        w.y = pack_bf2(fast_tanh(acc[mt][nt][2]), fast_tanh(acc[mt][nt][3]));
        *(uint2*)&hbuf[(mt * 16 + l16) * HSTRIDE + wave * UU + nt * 16 + quad * 4] = w;
      }
    }
    __syncthreads();
  }

  // ---- final: Aop = WoT rows (o), Bop = h rows; 16 rows per wave ----
  short8 wof[8];
#pragma unroll
  for (int ks = 0; ks < 8; ks++)
    wof[ks] = *(const short8*)&WoT[l16 * DD + ks * 32 + quad * 8];

  floatx4 accf = {0.f, 0.f, 0.f, 0.f};
#pragma unroll
  for (int ks = 0; ks < 8; ks++) {
    short8 bfr = *(const short8*)&hbuf[(wave * 16 + l16) * HSTRIDE + ks * 32 + quad * 8];
    accf = __builtin_amdgcn_mfma_f32_16x16x32_bf16(wof[ks], bfr, accf, 0, 0, 0);
  }
  const long obase = (row0 + wave * 16 + l16) * OUTN;
  if (quad < 2) {
    float4 p = {accf[0] + bout[quad * 4 + 0], accf[1] + bout[quad * 4 + 1],
                accf[2] + bout[quad * 4 + 2], accf[3] + bout[quad * 4 + 3]};
    *(float4*)&out[obase + quad * 4] = p;
  } else if (quad == 2) {
    float2 p = {accf[0] + bout[8], accf[1] + bout[9]};
    *(float2*)&out[obase + 8] = p;
  }
}

extern "C" void kernel_launch(void* const* d_in, const int* in_sizes, int n_in,
                              void* d_out, int out_size, void* d_ws, size_t ws_size,
                              hipStream_t stream) {
  const float* x    = (const float*)d_in[0];   // (131072, 256) fp32
  const int*   idx  = (const int*)d_in[1];     // (3, 4, 128) int32
  const float* W    = (const float*)d_in[2];   // (3, 4, 128, 64) fp32
  const float* b    = (const float*)d_in[3];   // (3, 4, 64) fp32
  const float* Wout = (const float*)d_in[4];   // (256, 10) fp32
  const float* bout = (const float*)d_in[5];   // (10,) fp32
  float* out = (float*)d_out;                  // (131072, 10) fp32

  ushort_t* AT  = (ushort_t*)d_ws;             // 3*256*256 bf16
  ushort_t* WoT = AT + LL * DD * DD;           // 16*256 bf16

  prep_kernel<<<LL * DD + 16, 256, 0, stream>>>(idx, W, Wout, AT, WoT);
  fused_kernel<<<131072 / MROWS, 256, 0, stream>>>(x, b, bout, AT, WoT, out);
}